// Round 3
// baseline (2326.985 us; speedup 1.0000x reference)
//
#include <hip/hip_runtime.h>

// VQ nearest-codebook: x [262144,256] f32, emb [1024,256] f32
// out = concat(z_q [262144*256] f32, min_indices [262144] written as f32)
//
// Round 3: bitwise-replicate the numpy float32 reference:
//   d = rowsq(x)[:,None] + rowsq(emb)[None,:] - 2*sgemm(x, emb.T); argmin (first occurrence)
// - sgemm dot: ascending-k single-accumulator f32 FMA (OpenBLAS microkernel order)
// - rowsq: numpy reduce = first element + pairwise_sum(rest,255) with the
//   AVX512 (W=16) npyv block structure, squares rounded separately
// - final d: fl(fl(A+B) - 2*dot) -> quantized at ulp(~256); ties -> lowest index

constexpr int N_E   = 1024;
constexpr int E_DIM = 256;
constexpr int N_TOK = 262144;

constexpr int TM = 32;    // tokens per block
constexpr int TN = 128;   // embeddings per chunk (32 per wave)
constexpr int KK = 32;    // dims per k-tile

// separately-rounded square; asm barrier prevents fmac contraction into a later add
__device__ __forceinline__ float sqf(float v) {
    float p = v * v;
    asm volatile("" : "+v"(p));
    return p;
}

// numpy pairwise_sum block for 64 <= n <= 128 over SQUARES of b[0..n):
// npyv AVX512 path: r_q = lanes b[16q+L]; (init-only: loop bound n-(n%64)==64)
// lanewise (r0+r1)+(r2+r3) -> T_L; halving reduce U=T_L+T_{L+8}, V=U_L+U_{L+4},
// (V0+V2)+(V1+V3); sequential tail.
__device__ __forceinline__ float pwb(const float* b, int n) {
    float U[8];
#pragma unroll
    for (int L = 0; L < 8; ++L) {
        float TL  = (sqf(b[L])     + sqf(b[16 + L])) + (sqf(b[32 + L]) + sqf(b[48 + L]));
        float TL8 = (sqf(b[8 + L]) + sqf(b[24 + L])) + (sqf(b[40 + L]) + sqf(b[56 + L]));
        U[L] = TL + TL8;
    }
    float V0 = U[0] + U[4], V1 = U[1] + U[5], V2 = U[2] + U[6], V3 = U[3] + U[7];
    float res = (V0 + V2) + (V1 + V3);
    for (int i = 64; i < n; ++i) res += sqf(b[i]);
    return res;
}

// rowsq = sq(r[0]) + pairwise(sq(r[1:]), 255); 255 -> 120 + (64 + 71)
__global__ __launch_bounds__(64) void rowsq_kernel(const float* __restrict__ src,
                                                   float* __restrict__ dst) {
    __shared__ float rs[32][257];
    const int rowBase = blockIdx.x * 32;
    const int tid = threadIdx.x;
    const float4* s4 = reinterpret_cast<const float4*>(src);
    for (int i = tid; i < 32 * 64; i += 64) {
        int rr = i >> 6, c4 = i & 63;
        float4 v = s4[(size_t)(rowBase + rr) * 64 + c4];
        rs[rr][c4 * 4 + 0] = v.x;
        rs[rr][c4 * 4 + 1] = v.y;
        rs[rr][c4 * 4 + 2] = v.z;
        rs[rr][c4 * 4 + 3] = v.w;
    }
    __syncthreads();
    if (tid < 32) {
        const float* r = rs[tid];
        float left = pwb(r + 1, 120);    // elements 1..120
        float l2   = pwb(r + 121, 64);   // 121..184
        float r2   = pwb(r + 185, 71);   // 185..255
        dst[rowBase + tid] = sqf(r[0]) + (left + (l2 + r2));
    }
}

__global__ __launch_bounds__(256) void vq_kernel(const float* __restrict__ x,
                                                 const float* __restrict__ emb,
                                                 const float* __restrict__ Arow,
                                                 const float* __restrict__ Brow,
                                                 float* __restrict__ zq,
                                                 float* __restrict__ outIdx) {
    __shared__ float xs[E_DIM][TM];   // 32 KB transposed x tile
    __shared__ float es[KK][TN];      // 16 KB transposed emb k-tile
    __shared__ float wm1[4][TM];
    __shared__ int   wi1[4][TM];
    __shared__ int   fidx[TM];

    const int tid  = threadIdx.x;
    const int wave = tid >> 6;
    const int lane = tid & 63;
    const int t4   = lane & 7;    // token group: tokens 4*t4..+3
    const int e4   = lane >> 3;   // emb group within wave
    const int tokBase = blockIdx.x * TM;

    const float4* xf4 = reinterpret_cast<const float4*>(x);
    const float4* ef4 = reinterpret_cast<const float4*>(emb);

    // per-lane A values for its 4 tokens (read BEFORE this block overwrites outIdx)
    float aA[4];
#pragma unroll
    for (int i = 0; i < 4; ++i) aA[i] = Arow[tokBase + t4 * 4 + i];

    // stage x transposed: xs[d][t]
    for (int i = tid; i < TM * (E_DIM / 4); i += 256) {
        int t  = i >> 6;
        int c4 = i & 63;
        float4 v = xf4[(size_t)(tokBase + t) * (E_DIM / 4) + c4];
        xs[c4 * 4 + 0][t] = v.x;
        xs[c4 * 4 + 1][t] = v.y;
        xs[c4 * 4 + 2][t] = v.z;
        xs[c4 * 4 + 3][t] = v.w;
    }

    float m1[4];
    int   i1[4];
#pragma unroll
    for (int i = 0; i < 4; ++i) { m1[i] = 3.4e38f; i1[i] = 0; }

    for (int chunk = 0; chunk < N_E / TN; ++chunk) {
        float acc[4][4];
#pragma unroll
        for (int i = 0; i < 4; ++i)
#pragma unroll
            for (int j = 0; j < 4; ++j) acc[i][j] = 0.0f;

        for (int kt = 0; kt < E_DIM / KK; ++kt) {
            __syncthreads();  // protect previous es tile (covers xs staging at first iter)
            for (int i = tid; i < TN * (KK / 4); i += 256) {
                int e  = i >> 3;
                int c4 = i & 7;
                float4 v = ef4[(size_t)(chunk * TN + e) * (E_DIM / 4) + kt * (KK / 4) + c4];
                es[c4 * 4 + 0][e] = v.x;
                es[c4 * 4 + 1][e] = v.y;
                es[c4 * 4 + 2][e] = v.z;
                es[c4 * 4 + 3][e] = v.w;
            }
            __syncthreads();
            // ascending-k single-accumulator FMA == sgemm microkernel accumulation
#pragma unroll 4
            for (int k = 0; k < KK; ++k) {
                float4 xv = *reinterpret_cast<const float4*>(&xs[kt * KK + k][t4 * 4]);
                float4 ev = *reinterpret_cast<const float4*>(&es[k][wave * 32 + e4 * 4]);
                float xa[4] = {xv.x, xv.y, xv.z, xv.w};
                float ea[4] = {ev.x, ev.y, ev.z, ev.w};
#pragma unroll
                for (int i = 0; i < 4; ++i)
#pragma unroll
                    for (int j = 0; j < 4; ++j) acc[i][j] += xa[i] * ea[j];
            }
        }
        // replicate d = fl(fl(A+B) - 2*dot); running min, first-occurrence ties
#pragma unroll
        for (int j = 0; j < 4; ++j) {
            int   kg = chunk * TN + wave * 32 + e4 * 4 + j;
            float Bk = Brow[kg];
#pragma unroll
            for (int i = 0; i < 4; ++i) {
                float t = aA[i] + Bk;            // fl(A+B)
                float s = t - 2.0f * acc[i][j];  // fl(t - 2*dot)  (2*dot exact)
                if (s < m1[i]) { m1[i] = s; i1[i] = kg; }
            }
        }
    }

    // merge across e4 groups; ties -> smaller index (np.argmin first occurrence)
#pragma unroll
    for (int off = 8; off <= 32; off <<= 1) {
#pragma unroll
        for (int i = 0; i < 4; ++i) {
            float o1 = __shfl_xor(m1[i], off, 64);
            int   oi = __shfl_xor(i1[i], off, 64);
            if (o1 < m1[i] || (o1 == m1[i] && oi < i1[i])) { m1[i] = o1; i1[i] = oi; }
        }
    }
    if (lane < 8) {
#pragma unroll
        for (int i = 0; i < 4; ++i) {
            wm1[wave][lane * 4 + i] = m1[i];
            wi1[wave][lane * 4 + i] = i1[i];
        }
    }
    __syncthreads();
    if (tid < TM) {
        float bm1 = wm1[0][tid];
        int   bi1 = wi1[0][tid];
#pragma unroll
        for (int w = 1; w < 4; ++w) {
            float o1 = wm1[w][tid];
            int   oi = wi1[w][tid];
            if (o1 < bm1 || (o1 == bm1 && oi < bi1)) { bm1 = o1; bi1 = oi; }
        }
        outIdx[tokBase + tid] = (float)bi1;
        fidx[tid] = bi1;
    }
    __syncthreads();
    // gather z_q rows
    float4* zq4 = reinterpret_cast<float4*>(zq);
#pragma unroll
    for (int it = 0; it < TM * (E_DIM / 4) / 256; ++it) {
        int flat = it * 256 + tid;
        int t = flat >> 6, c = flat & 63;
        zq4[(size_t)(tokBase + t) * (E_DIM / 4) + c] = ef4[(size_t)fidx[t] * (E_DIM / 4) + c];
    }
}

extern "C" void kernel_launch(void* const* d_in, const int* in_sizes, int n_in,
                              void* d_out, int out_size, void* d_ws, size_t ws_size,
                              hipStream_t stream) {
    const float* x   = (const float*)d_in[0];
    const float* emb = (const float*)d_in[1];
    float* out    = (float*)d_out;
    float* zq     = out;
    float* outIdx = out + (size_t)N_TOK * E_DIM;
    float* Brow   = (float*)d_ws;            // ||e_k||^2 replicated (4 KB)

    // A (||x_n||^2 replicated) staged in the index region of d_out;
    // vq_kernel reads each block's A values before overwriting them with indices.
    float* Arow = outIdx;

    rowsq_kernel<<<N_TOK / 32, 64, 0, stream>>>(x, Arow);
    rowsq_kernel<<<N_E / 32, 64, 0, stream>>>(emb, Brow);
    vq_kernel<<<N_TOK / TM, 256, 0, stream>>>(x, emb, Arow, Brow, zq, outIdx);
}